// Round 10
// baseline (254.446 us; speedup 1.0000x reference)
//
#include <hip/hip_runtime.h>
#include <hip/hip_bf16.h>

#define NN    1024
#define DD    128
#define TILE  128
#define PITCH 136   // bf16 elems per LDS tile row: 128 + 8 pad
#define SQP   132   // f32 elems per LDS sq row: 128 + 4 pad
#define NBLK  1024

typedef __bf16 bf16_t;
typedef bf16_t bf16x8 __attribute__((ext_vector_type(8)));
typedef float  f32x4  __attribute__((ext_vector_type(4)));
typedef _Float16 half4 __attribute__((ext_vector_type(4)));

// ws layout: floats [0..83]; byte offset 1024: f16 sq buffer 16*1024*1024*2 B.
// [0] coord_sum [1] reg_sum [2] count_loss_sum [3] bce_sum
// [4+b] pos_sum [20+b] pos_cnt [36+b] neg_sum [68+b] pos_diag_cnt

__device__ __forceinline__ void async_load16(const void* g, void* l) {
  __builtin_amdgcn_global_load_lds(
      (const __attribute__((address_space(1))) void*)g,
      (__attribute__((address_space(3))) void*)l, 16, 0, 0);
}

__global__ __launch_bounds__(256) void small_losses(
    const float* __restrict__ pcoord, const float* __restrict__ pts,
    const float* __restrict__ masks,  const float* __restrict__ pcount,
    const float* __restrict__ adj,    float* __restrict__ ws) {
  __shared__ float sh[4][3];
  float coord = 0.f, cnt = 0.f, pd = 0.f;
  const int b = blockIdx.x;           // 16 blocks
  const int gt = b * 256 + threadIdx.x;
  const int stride = 16 * 256;

  const float4* a4 = (const float4*)pcoord;
  const float4* b4 = (const float4*)pts;
  for (int i = gt; i < 8192; i += stride) {
    float4 a = a4[i], bb = b4[i];
    float dx = a.x-bb.x, dy = a.y-bb.y, dz = a.z-bb.z, dw = a.w-bb.w;
    coord += dx*dx + dy*dy + dz*dz + dw*dw;
  }
  const float* m = masks + b * NN;
  const float* ad = adj + (size_t)b * NN * NN;
  for (int i = threadIdx.x; i < NN; i += 256) {
    cnt += m[i];
    pd  += (ad[(size_t)i * (NN + 1)] > 0.5f) ? 1.f : 0.f;  // diagonal positives
  }

  const int lane = threadIdx.x & 63, w = threadIdx.x >> 6;
  #pragma unroll
  for (int o = 32; o; o >>= 1) {
    coord += __shfl_xor(coord, o);
    cnt   += __shfl_xor(cnt, o);
    pd    += __shfl_xor(pd, o);
  }
  if (lane == 0) { sh[w][0] = coord; sh[w][1] = cnt; sh[w][2] = pd; }
  __syncthreads();
  if (threadIdx.x == 0) {
    float c = 0.f, n = 0.f, p = 0.f;
    for (int i = 0; i < 4; ++i) { c += sh[i][0]; n += sh[i][1]; p += sh[i][2]; }
    atomicAdd(&ws[0], c);
    float d = fabsf(pcount[b] - n);
    float term = (d < 1.f) ? 0.5f * d * d : d - 0.5f;
    atomicAdd(&ws[2], term);
    ws[68 + b] = p;                   // one writer per batch
  }
}

// ---------------- kernel A: gram -> sq (f16) to global, diag zeroed ----------------
__global__ __launch_bounds__(512, 4) void gram_sq(
    const float* __restrict__ feat, _Float16* __restrict__ sqout,
    float* __restrict__ ws) {
  __shared__ __align__(16) char smem[2 * TILE * PITCH * sizeof(bf16_t)];
  bf16_t* lsA = (bf16_t*)smem;
  bf16_t* lsB = (bf16_t*)(smem + TILE * PITCH * sizeof(bf16_t));
  float*  sqb = (float*)smem;       // f32 overlay post-MFMA
  __shared__ float nrmA[TILE], nrmB[TILE];
  __shared__ float red[8];

  const int bx  = blockIdx.x;
  const int b   = bx >> 6;
  const int tid = bx & 63;
  const int ti  = (tid >> 3) << 7;
  const int tj  = (tid & 7)  << 7;
  const bool diag = ((tid >> 3) == (tid & 7));

  const int t = threadIdx.x;
  const float* fb = feat + (size_t)b * NN * DD;

  float regsum = 0.f;
  #pragma unroll
  for (int it = 0; it < 8; ++it) {
    int cid  = it * 512 + t;
    int tile = cid >> 11;
    int sub  = cid & 2047;
    int row  = sub >> 4;
    int c8   = sub & 15;
    const float* src = fb + (size_t)((tile ? tj : ti) + row) * DD + c8 * 8;
    float4 u = *(const float4*)src;
    float4 v = *(const float4*)(src + 4);
    if (diag && tile == 0)
      regsum += u.x*u.x + u.y*u.y + u.z*u.z + u.w*u.w
              + v.x*v.x + v.y*v.y + v.z*v.z + v.w*v.w;
    bf16_t* dst = (tile ? lsB : lsA) + row * PITCH + c8 * 8;
    dst[0] = (bf16_t)u.x; dst[1] = (bf16_t)u.y; dst[2] = (bf16_t)u.z; dst[3] = (bf16_t)u.w;
    dst[4] = (bf16_t)v.x; dst[5] = (bf16_t)v.y; dst[6] = (bf16_t)v.z; dst[7] = (bf16_t)v.w;
  }
  __syncthreads();

  {
    int row  = t >> 1;
    int half = t & 1;
    const bf16_t* src = (row < TILE ? lsA + row * PITCH : lsB + (row - TILE) * PITCH)
                        + half * 64;
    float s = 0.f;
    #pragma unroll
    for (int c = 0; c < 8; ++c) {
      bf16x8 ch = *(const bf16x8*)(src + c * 8);
      #pragma unroll
      for (int i = 0; i < 8; ++i) { float v = (float)ch[i]; s += v * v; }
    }
    s += __shfl_xor(s, 1);
    if (half == 0) { if (row < TILE) nrmA[row] = s; else nrmB[row - TILE] = s; }
  }

  const int lane = t & 63;
  const int wave = t >> 6;
  const int lrow = lane & 15;
  const int quad = lane >> 4;

  f32x4 acc[8];
  #pragma unroll
  for (int fc = 0; fc < 8; ++fc) acc[fc] = (f32x4){0.f, 0.f, 0.f, 0.f};

  #pragma unroll
  for (int k0 = 0; k0 < DD; k0 += 32) {
    const int kc = k0 + quad * 8;
    bf16x8 aF = *(const bf16x8*)&lsA[(wave * 16 + lrow) * PITCH + kc];
    bf16x8 bF[8];
    #pragma unroll
    for (int fc = 0; fc < 8; ++fc)
      bF[fc] = *(const bf16x8*)&lsB[(fc * 16 + lrow) * PITCH + kc];
    #pragma unroll
    for (int fc = 0; fc < 8; ++fc)
      acc[fc] = __builtin_amdgcn_mfma_f32_16x16x32_bf16(aF, bF[fc], acc[fc], 0, 0, 0);
  }
  __syncthreads();

  {
    const int rbase = wave * 16 + quad * 4;
    #pragma unroll
    for (int fc = 0; fc < 8; ++fc) {
      const int ctile = fc * 16 + lrow;
      const float ncol = nrmB[ctile];
      #pragma unroll
      for (int r = 0; r < 4; ++r) {
        const int rtile = rbase + r;
        sqb[rtile * SQP + ctile] = fmaxf(nrmA[rtile] + ncol - 2.f * acc[fc][r], 0.f);
      }
    }
  }
  __syncthreads();

  // coalesced f16 write-out; diag blocks zero their diagonal element so the
  // streaming kernel can treat all elements uniformly (corrected in finalize).
  {
    const int c4 = t & 31, r0 = t >> 5;
    _Float16* sb = sqout + (size_t)b * NN * NN + (size_t)(ti + r0) * NN + tj + c4 * 4;
    for (int it = 0; it < 8; ++it) {
      float4 s = *(const float4*)&sqb[(it * 16 + r0) * SQP + c4 * 4];
      if (diag) {
        int cc = (it * 16 + r0) - c4 * 4;
        if (cc >= 0 && cc < 4) ((float*)&s)[cc] = 0.f;
      }
      half4 h = { (_Float16)s.x, (_Float16)s.y, (_Float16)s.z, (_Float16)s.w };
      *(half4*)(sb + (size_t)it * 16 * NN) = h;
    }
  }

  if (diag) {
    #pragma unroll
    for (int o = 32; o; o >>= 1) regsum += __shfl_xor(regsum, o);
    if (lane == 0) red[wave] = regsum;
    __syncthreads();
    if (t == 0) {
      float s = 0.f;
      for (int w = 0; w < 8; ++w) s += red[w];
      atomicAdd(&ws[1], s);
    }
  }
}

// ---------------- kernel B: async-DMA streaming BCE + contrastive ----------------
// 2048 blocks x 256 threads; 8 rows/block; chunks of 1024 elements staged to LDS
// via global_load_lds (DMA queue holds in-flight data -> MLP without VGPRs).
__global__ __launch_bounds__(256) void bce_stream(
    const float* __restrict__ logits, const float* __restrict__ adj,
    const _Float16* __restrict__ sq, float* __restrict__ ws) {
  __shared__ __align__(16) char smem[2][10240];   // per buf: L 4K | A 4K | S 2K
  __shared__ float red[4][4];

  const int b   = blockIdx.x >> 7;
  const int blk = blockIdx.x & 127;
  const int t   = threadIdx.x;
  const int wv  = t >> 6;
  const size_t base = (size_t)b * NN * NN + (size_t)(blk * 8) * NN;
  const char* lpB = (const char*)(logits + base);
  const char* apB = (const char*)(adj + base);
  const char* spB = (const char*)(sq + base);

  // stage chunk c into buffer p (LDS dst is wave-uniform base; HW adds lane*16)
  #define STAGE(c, p)                                                   \
    do {                                                                \
      async_load16(lpB + (c) * 4096 + t * 16, smem[p] + wv * 1024);     \
      async_load16(apB + (c) * 4096 + t * 16, smem[p] + 4096 + wv * 1024); \
      if (t < 128)                                                      \
        async_load16(spB + (c) * 2048 + t * 16, smem[p] + 8192 + wv * 1024); \
    } while (0)

  float bsum = 0.f, poss = 0.f, posc = 0.f, negs = 0.f;
  STAGE(0, 0);
  for (int c = 0; c < 8; ++c) {
    const int p = c & 1;
    if (c < 7) STAGE(c + 1, p ^ 1);
    __syncthreads();                  // drains DMA (vmcnt) -> chunk c ready
    float4 L = *(const float4*)(smem[p] + t * 16);
    float4 A = *(const float4*)(smem[p] + 4096 + t * 16);
    half4  S = *(const half4*)(smem[p] + 8192 + t * 8);
    #pragma unroll
    for (int k = 0; k < 4; ++k) {
      float l = ((const float*)&L)[k];
      float a = ((const float*)&A)[k];
      float s = (float)S[k];
      bsum += fmaxf(l, 0.f) - l * a + __logf(1.f + __expf(-fabsf(l)));
      float h = fmaxf(1.f - sqrtf(fmaxf(s, 1e-12f)), 0.f);
      bool pos = a > 0.5f;
      poss += pos ? s : 0.f;
      posc += pos ? 1.f : 0.f;
      negs += pos ? 0.f : h * h;
    }
    __syncthreads();                  // protect buffer p before restage at c+1
  }
  #undef STAGE

  const int lane = t & 63, wave = t >> 6;
  #pragma unroll
  for (int o = 32; o; o >>= 1) {
    bsum += __shfl_xor(bsum, o);
    poss += __shfl_xor(poss, o);
    posc += __shfl_xor(posc, o);
    negs += __shfl_xor(negs, o);
  }
  if (lane == 0) {
    red[wave][0] = bsum; red[wave][1] = poss;
    red[wave][2] = posc; red[wave][3] = negs;
  }
  __syncthreads();
  if (t == 0) {
    float s0=0.f,s1=0.f,s2=0.f,s3=0.f;
    for (int w = 0; w < 4; ++w) {
      s0 += red[w][0]; s1 += red[w][1]; s2 += red[w][2]; s3 += red[w][3];
    }
    atomicAdd(&ws[3], s0);
    atomicAdd(&ws[4 + b], s1);
    atomicAdd(&ws[20 + b], s2);
    atomicAdd(&ws[36 + b], s3);
  }
}

__global__ void finalize(const float* __restrict__ ws, float* __restrict__ out) {
  if (threadIdx.x != 0 || blockIdx.x != 0) return;
  float coord = ws[0] / 32768.f;
  float reg   = ws[1] / 2097152.f;
  float cntl  = ws[2] / 16.f;
  float edge  = ws[3] / 16777216.f;
  // hinge value the stream kernel added for each (zeroed-sq) diagonal non-pos:
  float kk = fmaxf(1.f - sqrtf(fmaxf(0.f, 1e-12f)), 0.f);
  kk = kk * kk;
  float contra = 0.f;
  for (int b = 0; b < 16; ++b) {
    float posdiag = ws[68 + b];
    float posc    = ws[20 + b];
    float negcnt  = 1048576.f - 1024.f - posc + posdiag;   // N^2 - N - offdiag pos
    float negsum  = ws[36 + b] - (1024.f - posdiag) * kk;  // remove diag hinge
    float p = ws[4 + b] / fmaxf(posc, 1.f);
    float n = negsum / fmaxf(negcnt, 1.f);
    contra += p + n;
  }
  contra *= (1.f / 16.f);
  float total = coord + 2.f * edge + 0.1f * cntl + 0.001f * reg + 0.1f * contra;
  out[0] = total; out[1] = coord; out[2] = edge;
  out[3] = cntl;  out[4] = reg;   out[5] = contra;
}

extern "C" void kernel_launch(void* const* d_in, const int* in_sizes, int n_in,
                              void* d_out, int out_size, void* d_ws, size_t ws_size,
                              hipStream_t stream) {
  (void)in_sizes; (void)n_in; (void)out_size; (void)ws_size;
  const float* pcoord = (const float*)d_in[0];
  const float* pts    = (const float*)d_in[1];
  const float* logits = (const float*)d_in[2];
  const float* adj    = (const float*)d_in[3];
  const float* masks  = (const float*)d_in[4];
  const float* pcount = (const float*)d_in[5];
  const float* nf     = (const float*)d_in[6];
  float* ws  = (float*)d_ws;
  float* out = (float*)d_out;

  hipMemsetAsync(ws, 0, 84 * sizeof(float), stream);
  small_losses<<<16, 256, 0, stream>>>(pcoord, pts, masks, pcount, adj, ws);
  _Float16* sqbuf = (_Float16*)((char*)d_ws + 1024);
  gram_sq<<<NBLK, 512, 0, stream>>>(nf, sqbuf, ws);
  bce_stream<<<2048, 256, 0, stream>>>(logits, adj, sqbuf, ws);
  finalize<<<1, 64, 0, stream>>>(ws, out);
}

// Round 11
// 251.403 us; speedup vs baseline: 1.0121x; 1.0121x over previous
//
#include <hip/hip_runtime.h>
#include <hip/hip_bf16.h>

#define NN    1024
#define DD    128
#define TILE  128
#define PITCH 136   // bf16 elems per LDS tile row: 128 + 8 pad
#define SQP   132   // f32 elems per LDS sq row: 128 + 4 pad
#define NBLK  1024

typedef __bf16 bf16_t;
typedef bf16_t bf16x8 __attribute__((ext_vector_type(8)));
typedef float  f32x4  __attribute__((ext_vector_type(4)));
typedef _Float16 half4 __attribute__((ext_vector_type(4)));

// s_waitcnt immediates (gfx9 encoding): vmcnt(N) only, lgkm/exp unmasked
#define WAITVM6 0x0F76
#define WAITVM3 0x0F73
#define WAITVM0 0x0F70

// ws layout: floats [0..83]; byte offset 1024: f16 sq buffer 16*1024*1024*2 B.
// [0] coord_sum [1] reg_sum [2] count_loss_sum [3] bce_sum
// [4+b] pos_sum [20+b] pos_cnt [36+b] neg_sum [68+b] pos_diag_cnt

__device__ __forceinline__ void async_load16(const void* g, void* l) {
  __builtin_amdgcn_global_load_lds(
      (const __attribute__((address_space(1))) void*)g,
      (__attribute__((address_space(3))) void*)l, 16, 0, 0);
}

__global__ __launch_bounds__(256) void small_losses(
    const float* __restrict__ pcoord, const float* __restrict__ pts,
    const float* __restrict__ masks,  const float* __restrict__ pcount,
    const float* __restrict__ adj,    float* __restrict__ ws) {
  __shared__ float sh[4][3];
  float coord = 0.f, cnt = 0.f, pd = 0.f;
  const int b = blockIdx.x;           // 16 blocks
  const int gt = b * 256 + threadIdx.x;
  const int stride = 16 * 256;

  const float4* a4 = (const float4*)pcoord;
  const float4* b4 = (const float4*)pts;
  for (int i = gt; i < 8192; i += stride) {
    float4 a = a4[i], bb = b4[i];
    float dx = a.x-bb.x, dy = a.y-bb.y, dz = a.z-bb.z, dw = a.w-bb.w;
    coord += dx*dx + dy*dy + dz*dz + dw*dw;
  }
  const float* m = masks + b * NN;
  const float* ad = adj + (size_t)b * NN * NN;
  for (int i = threadIdx.x; i < NN; i += 256) {
    cnt += m[i];
    pd  += (ad[(size_t)i * (NN + 1)] > 0.5f) ? 1.f : 0.f;  // diagonal positives
  }

  const int lane = threadIdx.x & 63, w = threadIdx.x >> 6;
  #pragma unroll
  for (int o = 32; o; o >>= 1) {
    coord += __shfl_xor(coord, o);
    cnt   += __shfl_xor(cnt, o);
    pd    += __shfl_xor(pd, o);
  }
  if (lane == 0) { sh[w][0] = coord; sh[w][1] = cnt; sh[w][2] = pd; }
  __syncthreads();
  if (threadIdx.x == 0) {
    float c = 0.f, n = 0.f, p = 0.f;
    for (int i = 0; i < 4; ++i) { c += sh[i][0]; n += sh[i][1]; p += sh[i][2]; }
    atomicAdd(&ws[0], c);
    float d = fabsf(pcount[b] - n);
    float term = (d < 1.f) ? 0.5f * d * d : d - 0.5f;
    atomicAdd(&ws[2], term);
    ws[68 + b] = p;                   // one writer per batch
  }
}

// ---------------- kernel A: gram -> sq (f16) to global, diag zeroed ----------------
__global__ __launch_bounds__(512, 4) void gram_sq(
    const float* __restrict__ feat, _Float16* __restrict__ sqout,
    float* __restrict__ ws) {
  __shared__ __align__(16) char smem[2 * TILE * PITCH * sizeof(bf16_t)];
  bf16_t* lsA = (bf16_t*)smem;
  bf16_t* lsB = (bf16_t*)(smem + TILE * PITCH * sizeof(bf16_t));
  float*  sqb = (float*)smem;       // f32 overlay post-MFMA
  __shared__ float nrmA[TILE], nrmB[TILE];
  __shared__ float red[8];

  const int bx  = blockIdx.x;
  const int b   = bx >> 6;
  const int tid = bx & 63;
  const int ti  = (tid >> 3) << 7;
  const int tj  = (tid & 7)  << 7;
  const bool diag = ((tid >> 3) == (tid & 7));

  const int t = threadIdx.x;
  const float* fb = feat + (size_t)b * NN * DD;

  float regsum = 0.f;
  #pragma unroll
  for (int it = 0; it < 8; ++it) {
    int cid  = it * 512 + t;
    int tile = cid >> 11;
    int sub  = cid & 2047;
    int row  = sub >> 4;
    int c8   = sub & 15;
    const float* src = fb + (size_t)((tile ? tj : ti) + row) * DD + c8 * 8;
    float4 u = *(const float4*)src;
    float4 v = *(const float4*)(src + 4);
    if (diag && tile == 0)
      regsum += u.x*u.x + u.y*u.y + u.z*u.z + u.w*u.w
              + v.x*v.x + v.y*v.y + v.z*v.z + v.w*v.w;
    bf16_t* dst = (tile ? lsB : lsA) + row * PITCH + c8 * 8;
    dst[0] = (bf16_t)u.x; dst[1] = (bf16_t)u.y; dst[2] = (bf16_t)u.z; dst[3] = (bf16_t)u.w;
    dst[4] = (bf16_t)v.x; dst[5] = (bf16_t)v.y; dst[6] = (bf16_t)v.z; dst[7] = (bf16_t)v.w;
  }
  __syncthreads();

  {
    int row  = t >> 1;
    int half = t & 1;
    const bf16_t* src = (row < TILE ? lsA + row * PITCH : lsB + (row - TILE) * PITCH)
                        + half * 64;
    float s = 0.f;
    #pragma unroll
    for (int c = 0; c < 8; ++c) {
      bf16x8 ch = *(const bf16x8*)(src + c * 8);
      #pragma unroll
      for (int i = 0; i < 8; ++i) { float v = (float)ch[i]; s += v * v; }
    }
    s += __shfl_xor(s, 1);
    if (half == 0) { if (row < TILE) nrmA[row] = s; else nrmB[row - TILE] = s; }
  }

  const int lane = t & 63;
  const int wave = t >> 6;
  const int lrow = lane & 15;
  const int quad = lane >> 4;

  f32x4 acc[8];
  #pragma unroll
  for (int fc = 0; fc < 8; ++fc) acc[fc] = (f32x4){0.f, 0.f, 0.f, 0.f};

  #pragma unroll
  for (int k0 = 0; k0 < DD; k0 += 32) {
    const int kc = k0 + quad * 8;
    bf16x8 aF = *(const bf16x8*)&lsA[(wave * 16 + lrow) * PITCH + kc];
    bf16x8 bF[8];
    #pragma unroll
    for (int fc = 0; fc < 8; ++fc)
      bF[fc] = *(const bf16x8*)&lsB[(fc * 16 + lrow) * PITCH + kc];
    #pragma unroll
    for (int fc = 0; fc < 8; ++fc)
      acc[fc] = __builtin_amdgcn_mfma_f32_16x16x32_bf16(aF, bF[fc], acc[fc], 0, 0, 0);
  }
  __syncthreads();

  {
    const int rbase = wave * 16 + quad * 4;
    #pragma unroll
    for (int fc = 0; fc < 8; ++fc) {
      const int ctile = fc * 16 + lrow;
      const float ncol = nrmB[ctile];
      #pragma unroll
      for (int r = 0; r < 4; ++r) {
        const int rtile = rbase + r;
        sqb[rtile * SQP + ctile] = fmaxf(nrmA[rtile] + ncol - 2.f * acc[fc][r], 0.f);
      }
    }
  }
  __syncthreads();

  // coalesced f16 write-out; diag blocks zero their diagonal element so the
  // streaming kernel treats all elements uniformly (corrected in finalize).
  {
    const int c4 = t & 31, r0 = t >> 5;
    _Float16* sb = sqout + (size_t)b * NN * NN + (size_t)(ti + r0) * NN + tj + c4 * 4;
    for (int it = 0; it < 8; ++it) {
      float4 s = *(const float4*)&sqb[(it * 16 + r0) * SQP + c4 * 4];
      if (diag) {
        int cc = (it * 16 + r0) - c4 * 4;
        if (cc >= 0 && cc < 4) ((float*)&s)[cc] = 0.f;
      }
      half4 h = { (_Float16)s.x, (_Float16)s.y, (_Float16)s.z, (_Float16)s.w };
      *(half4*)(sb + (size_t)it * 16 * NN) = h;
    }
  }

  if (diag) {
    #pragma unroll
    for (int o = 32; o; o >>= 1) regsum += __shfl_xor(regsum, o);
    if (lane == 0) red[wave] = regsum;
    __syncthreads();
    if (t == 0) {
      float s = 0.f;
      for (int w = 0; w < 8; ++w) s += red[w];
      atomicAdd(&ws[1], s);
    }
  }
}

// ---------------- kernel B: barrier-free wave-autonomous DMA-ring streamer ----------------
// 2048 blocks x 256 thr (4 waves). Each WAVE owns 2 matrix rows (2048 elems) and a
// private 4-slot LDS ring; chunks of 256 elems staged by global_load_lds at
// prefetch distance 3 with manual s_waitcnt vmcnt(6/3/0) -- NEVER a barrier in
// the loop, so prefetches survive (the R10 failure was __syncthreads draining
// vmcnt to 0). 9 DMA loads (~7.7 KB) permanently in flight per wave.
__global__ __launch_bounds__(256) void bce_stream(
    const float* __restrict__ logits, const float* __restrict__ adj,
    const _Float16* __restrict__ sq, float* __restrict__ ws) {
  __shared__ __align__(16) char ring[4][4][2560];  // [wave][slot][L 1024|A 1024|S 512]
  __shared__ float red[4][4];

  const int t = threadIdx.x, lane = t & 63, wv = t >> 6;
  const int b   = blockIdx.x >> 7;
  const int blk = blockIdx.x & 127;
  // wave's span: rows [blk*8 + wv*2, +2) of batch b = 2048 contiguous elems
  const size_t ebase = (size_t)b * NN * NN + (size_t)blk * 8 * NN + (size_t)wv * 2048;
  const char* lp = (const char*)(logits + ebase);
  const char* ap = (const char*)(adj + ebase);
  const char* sp = (const char*)(sq + ebase);

  #define STAGE(c)                                                        \
    do {                                                                  \
      char* dst_ = &ring[wv][(c) & 3][0];                                 \
      async_load16(lp + (c) * 1024 + lane * 16, dst_);                    \
      async_load16(ap + (c) * 1024 + lane * 16, dst_ + 1024);             \
      if (lane < 32) async_load16(sp + (c) * 512 + lane * 16, dst_ + 2048); \
    } while (0)

  STAGE(0); STAGE(1); STAGE(2);      // 9 loads outstanding

  float bsum = 0.f, poss = 0.f, posc = 0.f, negs = 0.f;
  #pragma unroll
  for (int c = 0; c < 8; ++c) {
    // wait for chunk c's 3 loads (leave newer chunks in flight)
    if (c <= 5)      __builtin_amdgcn_s_waitcnt(WAITVM6);
    else if (c == 6) __builtin_amdgcn_s_waitcnt(WAITVM3);
    else             __builtin_amdgcn_s_waitcnt(WAITVM0);
    const char* dst = &ring[wv][c & 3][0];
    float4 L = *(const float4*)(dst + lane * 16);
    float4 A = *(const float4*)(dst + 1024 + lane * 16);
    half4  S = *(const half4*)(dst + 2048 + lane * 8);
    #pragma unroll
    for (int k = 0; k < 4; ++k) {
      float l = ((const float*)&L)[k];
      float a = ((const float*)&A)[k];
      float s = (float)S[k];
      bsum += fmaxf(l, 0.f) - l * a + __logf(1.f + __expf(-fabsf(l)));
      float h = fmaxf(1.f - sqrtf(fmaxf(s, 1e-12f)), 0.f);
      bool pos = a > 0.5f;
      poss += pos ? s : 0.f;
      posc += pos ? 1.f : 0.f;
      negs += pos ? 0.f : h * h;
    }
    if (c + 3 < 8) STAGE(c + 3);     // restage slot consumed last iteration
  }
  #undef STAGE

  #pragma unroll
  for (int o = 32; o; o >>= 1) {
    bsum += __shfl_xor(bsum, o);
    poss += __shfl_xor(poss, o);
    posc += __shfl_xor(posc, o);
    negs += __shfl_xor(negs, o);
  }
  if (lane == 0) {
    red[wv][0] = bsum; red[wv][1] = poss;
    red[wv][2] = posc; red[wv][3] = negs;
  }
  __syncthreads();
  if (t == 0) {
    float s0=0.f,s1=0.f,s2=0.f,s3=0.f;
    for (int w = 0; w < 4; ++w) {
      s0 += red[w][0]; s1 += red[w][1]; s2 += red[w][2]; s3 += red[w][3];
    }
    atomicAdd(&ws[3], s0);
    atomicAdd(&ws[4 + b], s1);
    atomicAdd(&ws[20 + b], s2);
    atomicAdd(&ws[36 + b], s3);
  }
}

__global__ void finalize(const float* __restrict__ ws, float* __restrict__ out) {
  if (threadIdx.x != 0 || blockIdx.x != 0) return;
  float coord = ws[0] / 32768.f;
  float reg   = ws[1] / 2097152.f;
  float cntl  = ws[2] / 16.f;
  float edge  = ws[3] / 16777216.f;
  // hinge value the stream kernel added for each (zeroed-sq) diagonal non-pos:
  float kk = fmaxf(1.f - sqrtf(fmaxf(0.f, 1e-12f)), 0.f);
  kk = kk * kk;
  float contra = 0.f;
  for (int b = 0; b < 16; ++b) {
    float posdiag = ws[68 + b];
    float posc    = ws[20 + b];
    float negcnt  = 1048576.f - 1024.f - posc + posdiag;   // N^2 - N - offdiag pos
    float negsum  = ws[36 + b] - (1024.f - posdiag) * kk;  // remove diag hinge
    float p = ws[4 + b] / fmaxf(posc, 1.f);
    float n = negsum / fmaxf(negcnt, 1.f);
    contra += p + n;
  }
  contra *= (1.f / 16.f);
  float total = coord + 2.f * edge + 0.1f * cntl + 0.001f * reg + 0.1f * contra;
  out[0] = total; out[1] = coord; out[2] = edge;
  out[3] = cntl;  out[4] = reg;   out[5] = contra;
}

extern "C" void kernel_launch(void* const* d_in, const int* in_sizes, int n_in,
                              void* d_out, int out_size, void* d_ws, size_t ws_size,
                              hipStream_t stream) {
  (void)in_sizes; (void)n_in; (void)out_size; (void)ws_size;
  const float* pcoord = (const float*)d_in[0];
  const float* pts    = (const float*)d_in[1];
  const float* logits = (const float*)d_in[2];
  const float* adj    = (const float*)d_in[3];
  const float* masks  = (const float*)d_in[4];
  const float* pcount = (const float*)d_in[5];
  const float* nf     = (const float*)d_in[6];
  float* ws  = (float*)d_ws;
  float* out = (float*)d_out;

  hipMemsetAsync(ws, 0, 84 * sizeof(float), stream);
  small_losses<<<16, 256, 0, stream>>>(pcoord, pts, masks, pcount, adj, ws);
  _Float16* sqbuf = (_Float16*)((char*)d_ws + 1024);
  gram_sq<<<NBLK, 512, 0, stream>>>(nf, sqbuf, ws);
  bce_stream<<<2048, 256, 0, stream>>>(logits, adj, sqbuf, ws);
  finalize<<<1, 64, 0, stream>>>(ws, out);
}